// Round 8
// baseline (290.777 us; speedup 1.0000x reference)
//
#include <hip/hip_runtime.h>
#include <math.h>

#define KTOP 200
#define NPART 32
#define BLOCK 512
#define NHIST 2048
#define CAND_CAP 2048
#define WCAP 256
#define SSTAR 24           // sample order statistic (of 512) -> E[cand] ~ 940
#define TS 2048            // tile points; 1536 float4 = 24 KB
#define MAX_RETRY 4

typedef unsigned long long ull;

// d2 exactly as numpy: ((dx*dx + dy*dy) + dz*dz), no fma contraction
__device__ __forceinline__ float d2_ref(float ax, float ay, float az,
                                        float bx, float by, float bz) {
    float dx = __fsub_rn(ax, bx), dy = __fsub_rn(ay, by), dz = __fsub_rn(az, bz);
    return __fadd_rn(__fadd_rn(__fmul_rn(dx, dx), __fmul_rn(dy, dy)), __fmul_rn(dz, dz));
}

__device__ __forceinline__ unsigned key_of(const float* __restrict__ fus, int j,
                                           float vx, float vy, float vz) {
    return __float_as_uint(d2_ref(vx, vy, vz, fus[3*j], fus[3*j+1], fus[3*j+2]));
}

// shape-context bin of rel = p_j - q0, mirroring the reference f32 math
__device__ __forceinline__ int compute_bin(float rx, float ry, float rz) {
    const float TWO_PI_F = (float)6.283185307179586;
    const float PI_F     = (float)3.141592653589793;
    const float XY_W     = (float)(6.283185307179586 / 4.0);
    const float ZY_W     = (float)(3.141592653589793 / 4.0);

    float d2 = __fadd_rn(__fadd_rn(__fmul_rn(rx, rx), __fmul_rn(ry, ry)), __fmul_rn(rz, rz));
    float D  = sqrtf(__fadd_rn(d2, 1e-7f));
    float dist_bin;
    if (D >= 4.0f)      dist_bin = 1.0f;
    else if (D >= 1.0f) dist_bin = 0.0f;
    else                return -1;

    float axy = fmodf(atan2f(ry, rx) + TWO_PI_F, TWO_PI_F);
    float azy = fmodf(atan2f(ry, rz) + TWO_PI_F, PI_F);
    float xyb = floorf(__fdiv_rn(axy, XY_W));
    float zyb = floorf(__fdiv_rn(azy, ZY_W));
    if (!(xyb >= 0.0f && zyb >= 0.0f)) return -1;
    float ab  = xyb * 4.0f + zyb;
    int bin = (int)(dist_bin * 16.0f + ab);
    return bin;
}

__global__ __launch_bounds__(BLOCK, 6)
void shape_context_kernel(const float* __restrict__ veh,
                          const float* __restrict__ fus,
                          float* __restrict__ out,
                          int nfus) {
    const int b   = blockIdx.x;
    const int tid = threadIdx.x;
    const int lane = tid & 63;
    const int wid  = tid >> 6;

    // tile buffer (phase 2) and selection histogram (phases 1/3) time-share this region
    __shared__ __align__(16) char smem[TS * 12];            // 24576 B
    float4*   tile4 = (float4*)smem;
    unsigned* hist  = (unsigned*)smem;                      // 8 KB <= 24 KB

    __shared__ ull cand[CAND_CAP];                          // 16 KB
    __shared__ int wlist[WCAP];
    __shared__ unsigned hist32[NPART];
    __shared__ unsigned waveTot[BLOCK / 64], waveBase[BLOCK / 64];
    __shared__ unsigned s_bucket, s_rem, s_bcount, s_pivot;
    __shared__ int s_candCount, s_wcount, s_tc;
    __shared__ ull s_minPacked, s_serMin, s_lowBound;

    const float vx = veh[3*b], vy = veh[3*b+1], vz = veh[3*b+2];
    const float4* g4 = (const float4*)fus;
    const int nq4 = nfus & ~3;
    const int ntile = (nq4 + TS - 1) / TS;

    if (tid == 0) { s_minPacked = ~0ull; s_wcount = 0; }
    if (tid < NPART) hist32[tid] = 0;

    // my sample key (cached in a register; reused across pivot retries)
    const unsigned myKey = key_of(fus, (int)(((long long)tid * nfus) / BLOCK), vx, vy, vz);

    // block-wide: find bucket where cumulative hist count crosses remq
    auto find_bucket = [&](unsigned remq) {
        const int PER = NHIST / BLOCK;  // 4
        int base = tid * PER;
        unsigned c[PER];
        unsigned p = 0;
        #pragma unroll
        for (int i = 0; i < PER; i++) { c[i] = hist[base + i]; p += c[i]; }
        unsigned incl = p;
        #pragma unroll
        for (int d = 1; d < 64; d <<= 1) {
            unsigned n = __shfl_up(incl, d, 64);
            if (lane >= d) incl += n;
        }
        if (lane == 63) waveTot[wid] = incl;
        __syncthreads();
        if (tid == 0) {
            unsigned acc = 0;
            for (int w = 0; w < BLOCK / 64; w++) { waveBase[w] = acc; acc += waveTot[w]; }
        }
        __syncthreads();
        unsigned excl = waveBase[wid] + incl - p;
        if (excl < remq && remq <= excl + p) {  // unique crossing thread
            unsigned cum = excl;
            #pragma unroll
            for (int i = 0; i < PER; i++) {
                if (cum + c[i] >= remq) { s_bucket = base + i; s_rem = remq - cum; s_bcount = c[i]; break; }
                cum += c[i];
            }
        }
        __syncthreads();
    };

    // ================== pivot + tiled scan, with monotone retry ==================
    int sstar = SSTAR;
    int cnt = 0;
    bool needRadix = false;
    for (int attempt = 0; attempt < MAX_RETRY; ++attempt) {
        // ---- exact sample order-stat pivot key ----
        __syncthreads();
        for (int i = tid; i < NHIST; i += BLOCK) hist[i] = 0;
        if (tid == 0) s_tc = 0;
        __syncthreads();
        atomicAdd(&hist[myKey >> 21], 1u);
        __syncthreads();
        find_bucket((unsigned)sstar);
        const unsigned Ts = s_bucket, rems = s_rem;
        if ((myKey >> 21) == Ts) {
            int p = atomicAdd(&s_tc, 1);
            cand[p] = ((ull)myKey << 32) | (unsigned)tid;   // tc <= 512 < CAND_CAP
        }
        __syncthreads();
        const int tc = s_tc;
        for (int i = tid; i < tc; i += BLOCK) {
            ull me = cand[i];
            int rank = 0;
            for (int k2 = 0; k2 < tc; k2++) rank += (cand[k2] < me) ? 1 : 0;
            if (rank == (int)rems - 1) s_pivot = (unsigned)(me >> 32);
        }
        __syncthreads();
        const unsigned pivotKey = s_pivot;

        // ---- register-double-buffered tiled scan (coalesced) ----
        if (tid == 0) s_candCount = 0;
        __syncthreads();   // also: pivot-phase hist reads done before tile overwrites

        float4 r0 = {}, r1 = {}, r2 = {};
        {
            int nn = min(TS, nq4), nnf4 = (nn * 3) >> 2;
            if (tid < nnf4)        r0 = g4[tid];
            if (tid + 512 < nnf4)  r1 = g4[tid + 512];
            if (tid + 1024 < nnf4) r2 = g4[tid + 1024];
        }
        for (int t = 0; t < ntile; ++t) {
            int base = t * TS;
            int npts = min(TS, nq4 - base);
            int nf4  = (npts * 3) >> 2;
            if (tid < nf4)        tile4[tid] = r0;          // vmcnt wait lands here
            if (tid + 512 < nf4)  tile4[tid + 512] = r1;
            if (tid + 1024 < nf4) tile4[tid + 1024] = r2;
            if (t + 1 < ntile) {                            // prefetch next tile
                int nb = (t + 1) * TS, nn = min(TS, nq4 - nb);
                int nnf4 = (nn * 3) >> 2, ng = (nb * 3) >> 2;
                if (tid < nnf4)        r0 = g4[ng + tid];
                if (tid + 512 < nnf4)  r1 = g4[ng + tid + 512];
                if (tid + 1024 < nnf4) r2 = g4[ng + tid + 1024];
            }
            __syncthreads();                                // tile visible
            int quads = npts >> 2;
            if (tid < quads) {
                float4 A  = tile4[3 * tid];
                float4 Bq = tile4[3 * tid + 1];
                float4 Cq = tile4[3 * tid + 2];
                unsigned k0 = __float_as_uint(d2_ref(vx, vy, vz, A.x,  A.y,  A.z));
                unsigned k1 = __float_as_uint(d2_ref(vx, vy, vz, A.w,  Bq.x, Bq.y));
                unsigned k2 = __float_as_uint(d2_ref(vx, vy, vz, Bq.z, Bq.w, Cq.x));
                unsigned k3 = __float_as_uint(d2_ref(vx, vy, vz, Cq.y, Cq.z, Cq.w));
                int jb = base + 4 * tid;
                if (k0 <= pivotKey) { int pos = atomicAdd(&s_candCount, 1); if (pos < CAND_CAP) cand[pos] = ((ull)k0 << 32) | (unsigned)(jb + 0); }
                if (k1 <= pivotKey) { int pos = atomicAdd(&s_candCount, 1); if (pos < CAND_CAP) cand[pos] = ((ull)k1 << 32) | (unsigned)(jb + 1); }
                if (k2 <= pivotKey) { int pos = atomicAdd(&s_candCount, 1); if (pos < CAND_CAP) cand[pos] = ((ull)k2 << 32) | (unsigned)(jb + 2); }
                if (k3 <= pivotKey) { int pos = atomicAdd(&s_candCount, 1); if (pos < CAND_CAP) cand[pos] = ((ull)k3 << 32) | (unsigned)(jb + 3); }
            }
            __syncthreads();                                // compute done before next commit
        }
        for (int j = nq4 + tid; j < nfus; j += BLOCK) {     // sub-quad tail
            unsigned k = key_of(fus, j, vx, vy, vz);
            if (k <= pivotKey) { int pos = atomicAdd(&s_candCount, 1); if (pos < CAND_CAP) cand[pos] = ((ull)k << 32) | (unsigned)j; }
        }
        __syncthreads();
        cnt = s_candCount;
        if (cnt >= KTOP && cnt <= CAND_CAP) break;
        if (cnt < KTOP) { if (sstar >= 256) { needRadix = true; break; } sstar *= 2; }
        else           { if (sstar <= 3)   { needRadix = true; break; } sstar >>= 1; }
        if (attempt == MAX_RETRY - 1) needRadix = true;
    }

    unsigned rem = 0;

    if (!needRadix) {
        // ---- exact top-KTOP among cnt candidates ----
        ull lm = ~0ull;
        for (int i = tid; i < cnt; i += BLOCK) lm = min(lm, cand[i]);
        #pragma unroll
        for (int d = 32; d > 0; d >>= 1) {
            ull o = __shfl_xor(lm, d, 64);
            lm = (o < lm) ? o : lm;
        }
        if (lane == 0) atomicMin(&s_minPacked, lm);

        for (int i = tid; i < NHIST; i += BLOCK) hist[i] = 0;
        __syncthreads();
        for (int i = tid; i < cnt; i += BLOCK) atomicAdd(&hist[(unsigned)(cand[i] >> 53)], 1u);
        __syncthreads();
        find_bucket(KTOP);
        const unsigned T2 = s_bucket;
        rem = s_rem;

        for (int i = tid; i < cnt; i += BLOCK) {
            ull me = cand[i];
            if ((unsigned)(me >> 53) < T2) {
                int pos = atomicAdd(&s_wcount, 1);
                if (pos < WCAP) wlist[pos] = (int)(me & 0xFFFFFFFFull);
            }
        }
        for (int i = tid; i < cnt; i += BLOCK) {
            ull me = cand[i];
            if ((unsigned)(me >> 53) == T2) {
                int rank = 0;
                for (int k2 = 0; k2 < cnt; k2++) {
                    ull o = cand[k2];
                    rank += ((unsigned)(o >> 53) == T2 && o < me) ? 1 : 0;
                }
                if (rank < (int)rem) {
                    int pos = atomicAdd(&s_wcount, 1);
                    if (pos < WCAP) wlist[pos] = (int)(me & 0xFFFFFFFFull);
                }
            }
        }
        __syncthreads();
    } else {
        // ---- exact radix-select fallback (never expected; reload-based) ----
        if (tid == 0) { s_candCount = 0; s_wcount = 0; }
        for (int i = tid; i < NHIST; i += BLOCK) hist[i] = 0;
        __syncthreads();
        for (int j = tid; j < nfus; j += BLOCK)
            atomicAdd(&hist[key_of(fus, j, vx, vy, vz) >> 21], 1u);
        __syncthreads();
        find_bucket(KTOP);
        unsigned T = s_bucket;
        rem = s_rem;
        unsigned bcount = s_bcount;
        int shift = 21;

        while (bcount > CAND_CAP && shift > 0) {
            int newshift = (shift > 11) ? (shift - 11) : 0;
            unsigned digmask = (1u << (shift - newshift)) - 1;
            __syncthreads();
            for (int i = tid; i < NHIST; i += BLOCK) hist[i] = 0;
            __syncthreads();
            for (int j = tid; j < nfus; j += BLOCK) {
                unsigned k = key_of(fus, j, vx, vy, vz);
                if ((k >> shift) == T) atomicAdd(&hist[(k >> newshift) & digmask], 1u);
            }
            __syncthreads();
            find_bucket(rem);
            T = (T << (shift - newshift)) | s_bucket;
            rem = s_rem;
            bcount = s_bcount;
            shift = newshift;
        }

        for (int j = tid; j < nfus; j += BLOCK) {
            unsigned k = key_of(fus, j, vx, vy, vz);
            unsigned hi = k >> shift;
            if (hi < T) {
                int pos = atomicAdd(&s_wcount, 1);
                if (pos < WCAP) wlist[pos] = j;
                atomicMin(&s_minPacked, ((ull)k << 32) | (unsigned)j);
            } else if (hi == T) {
                int pos = atomicAdd(&s_candCount, 1);
                if (pos < CAND_CAP) cand[pos] = ((ull)k << 32) | (unsigned)j;
                atomicMin(&s_minPacked, ((ull)k << 32) | (unsigned)j);
            }
        }
        __syncthreads();
        const int fcnt = s_candCount;
        if (fcnt <= CAND_CAP) {
            for (int i = tid; i < fcnt; i += BLOCK) {
                ull me = cand[i];
                int rank = 0;
                for (int k2 = 0; k2 < fcnt; k2++) rank += (cand[k2] < me) ? 1 : 0;
                if (rank < (int)rem) {
                    int pos = atomicAdd(&s_wcount, 1);
                    if (pos < WCAP) wlist[pos] = (int)(me & 0xFFFFFFFFull);
                }
            }
            __syncthreads();
        } else {
            // pathological: serial stable extraction among boundary keys
            const int idx0f = (int)(s_minPacked & 0xFFFFFFFFull);
            const float fq0x = fus[idx0f * 3], fq0y = fus[idx0f * 3 + 1], fq0z = fus[idx0f * 3 + 2];
            if (tid == 0) s_lowBound = 0;
            __syncthreads();
            for (unsigned itx = 0; itx < rem; ++itx) {
                if (tid == 0) s_serMin = ~0ull;
                __syncthreads();
                ull lowB = s_lowBound;
                ull lmx = ~0ull;
                for (int j = tid; j < nfus; j += BLOCK) {
                    unsigned k = key_of(fus, j, vx, vy, vz);
                    if ((k >> shift) == T) {
                        ull p = ((ull)k << 32) | (unsigned)j;
                        if (p >= lowB && p < lmx) lmx = p;
                    }
                }
                #pragma unroll
                for (int d = 32; d > 0; d >>= 1) {
                    ull o = __shfl_xor(lmx, d, 64);
                    lmx = (o < lmx) ? o : lmx;
                }
                if (lane == 0) atomicMin(&s_serMin, lmx);
                __syncthreads();
                if (tid == 0) {
                    int jm = (int)(s_serMin & 0xFFFFFFFFull);
                    float fx = fus[jm * 3], fy = fus[jm * 3 + 1], fz = fus[jm * 3 + 2];
                    int bin = compute_bin(__fsub_rn(fx, fq0x), __fsub_rn(fy, fq0y), __fsub_rn(fz, fq0z));
                    if (bin >= 0 && bin < NPART) hist32[bin] += 1u;
                    s_lowBound = s_serMin + 1;
                }
                __syncthreads();
            }
        }
    }

    // ---- common: q0 = stable nearest; winners -> shape-context bins ----
    const int idx0 = (int)(s_minPacked & 0xFFFFFFFFull);
    const float q0x = fus[idx0 * 3], q0y = fus[idx0 * 3 + 1], q0z = fus[idx0 * 3 + 2];
    {
        int wc = s_wcount; if (wc > WCAP) wc = WCAP;
        for (int i = tid; i < wc; i += BLOCK) {
            int j = wlist[i];
            float fx = fus[3 * j], fy = fus[3 * j + 1], fz = fus[3 * j + 2];
            int bin = compute_bin(__fsub_rn(fx, q0x), __fsub_rn(fy, q0y), __fsub_rn(fz, q0z));
            if (bin >= 0 && bin < NPART) atomicAdd(&hist32[bin], 1u);
        }
    }
    __syncthreads();

    // ---- epilogue (lanes 0..31 of wave 0): counts+1 -> L2-normalize*4 -> softmax ----
    if (tid < NPART) {
        float c = (float)hist32[tid] + 1.0f;
        float ss = __fmul_rn(c, c);
        #pragma unroll
        for (int d = 16; d > 0; d >>= 1) ss += __shfl_xor(ss, d, 64);
        float v = __fmul_rn(__fdiv_rn(c, sqrtf(ss)), 4.0f);
        float mx = v;
        #pragma unroll
        for (int d = 16; d > 0; d >>= 1) mx = fmaxf(mx, __shfl_xor(mx, d, 64));
        float e = expf(v - mx);
        float sum = e;
        #pragma unroll
        for (int d = 16; d > 0; d >>= 1) sum += __shfl_xor(sum, d, 64);
        out[b * NPART + tid] = __fdiv_rn(e, sum);
    }
}

extern "C" void kernel_launch(void* const* d_in, const int* in_sizes, int n_in,
                              void* d_out, int out_size, void* d_ws, size_t ws_size,
                              hipStream_t stream) {
    const float* veh = (const float*)d_in[0];   // (1024, 3)
    const float* fus = (const float*)d_in[1];   // (20000, 3)
    float* out = (float*)d_out;                 // (1024, 32)
    int nveh = in_sizes[0] / 3;
    int nfus = in_sizes[1] / 3;
    shape_context_kernel<<<nveh, BLOCK, 0, stream>>>(veh, fus, out, nfus);
}

// Round 9
// 94.905 us; speedup vs baseline: 3.0639x; 3.0639x over previous
//
#include <hip/hip_runtime.h>
#include <hip/hip_fp16.h>
#include <math.h>

#define KTOP 200
#define NPART 32
#define BLOCK 512
#define NHIST 2048
#define ACAP 3072          // approx-filter candidate indices
#define CAND_CAP 2048      // exact (key,idx) candidates
#define TLIST_CAP 1536     // boundary-bucket list (aliases acand)
#define WCAP 256
#define SSTAR 24           // sample order stat (of 512) -> E[below] ~ 936
#define MAX_RETRY 6

typedef unsigned long long ull;

// d2 exactly as numpy: ((dx*dx + dy*dy) + dz*dz), no fma contraction
__device__ __forceinline__ float d2_ref(float ax, float ay, float az,
                                        float bx, float by, float bz) {
    float dx = __fsub_rn(ax, bx), dy = __fsub_rn(ay, by), dz = __fsub_rn(az, bz);
    return __fadd_rn(__fadd_rn(__fmul_rn(dx, dx), __fmul_rn(dy, dy)), __fmul_rn(dz, dz));
}

__device__ __forceinline__ unsigned key_of(const float* __restrict__ fus, int j,
                                           float vx, float vy, float vz) {
    return __float_as_uint(d2_ref(vx, vy, vz, fus[3*j], fus[3*j+1], fus[3*j+2]));
}

// shape-context bin of rel = p_j - q0, mirroring the reference f32 math
__device__ __forceinline__ int compute_bin(float rx, float ry, float rz) {
    const float TWO_PI_F = (float)6.283185307179586;
    const float PI_F     = (float)3.141592653589793;
    const float XY_W     = (float)(6.283185307179586 / 4.0);
    const float ZY_W     = (float)(3.141592653589793 / 4.0);

    float d2 = __fadd_rn(__fadd_rn(__fmul_rn(rx, rx), __fmul_rn(ry, ry)), __fmul_rn(rz, rz));
    float D  = sqrtf(__fadd_rn(d2, 1e-7f));
    float dist_bin;
    if (D >= 4.0f)      dist_bin = 1.0f;
    else if (D >= 1.0f) dist_bin = 0.0f;
    else                return -1;

    float axy = fmodf(atan2f(ry, rx) + TWO_PI_F, TWO_PI_F);
    float azy = fmodf(atan2f(ry, rz) + TWO_PI_F, PI_F);
    float xyb = floorf(__fdiv_rn(axy, XY_W));
    float zyb = floorf(__fdiv_rn(azy, ZY_W));
    if (!(xyb >= 0.0f && zyb >= 0.0f)) return -1;
    float ab  = xyb * 4.0f + zyb;
    int bin = (int)(dist_bin * 16.0f + ab);
    return bin;
}

__device__ __forceinline__ float2 h2f2(unsigned u) {
    __half2 h = *reinterpret_cast<__half2*>(&u);
    return __half22float2(h);
}

// ---- kernel 1: compress fus -> fp16 (hx,hy,hz,0), 8 B/point, padded with +inf ----
__global__ __launch_bounds__(256)
void compress_kernel(const float* __restrict__ fus, uint2* __restrict__ hbuf,
                     int nfus, int npad) {
    int j = blockIdx.x * 256 + threadIdx.x;
    if (j >= npad) return;
    if (j < nfus) {
        unsigned short bx = __half_as_ushort(__float2half(fus[3*j]));
        unsigned short by = __half_as_ushort(__float2half(fus[3*j+1]));
        unsigned short bz = __half_as_ushort(__float2half(fus[3*j+2]));
        hbuf[j] = make_uint2((unsigned)bx | ((unsigned)by << 16), (unsigned)bz);
    } else {
        hbuf[j] = make_uint2(0x7C007C00u, 0x7C00u);   // +inf pad -> always filtered
    }
}

__global__ __launch_bounds__(BLOCK, 8)
void shape_context_kernel(const float* __restrict__ veh,
                          const float* __restrict__ fus,
                          const uint4* __restrict__ h4,   // compressed, 2 points per uint4
                          float* __restrict__ out,
                          int nfus, int npad) {
    const int b   = blockIdx.x;
    const int tid = threadIdx.x;
    const int lane = tid & 63;
    const int wid  = tid >> 6;

    __shared__ unsigned hist[NHIST];                  // also: skeys[512] during pivot
    __shared__ int acand[ACAP];                       // also: tlist (ull[TLIST_CAP])
    __shared__ ull cand[CAND_CAP];
    __shared__ int wlist[WCAP];
    __shared__ unsigned hist32[NPART];
    __shared__ unsigned waveTot[BLOCK / 64], waveBase[BLOCK / 64];
    __shared__ unsigned s_bucket, s_rem, s_bcount, s_pivot;
    __shared__ int s_apx, s_candCount, s_wcount, s_tc;
    __shared__ ull s_minPacked, s_serMin, s_lowBound;

    unsigned* skeys = hist;
    ull* tlist = (ull*)acand;

    const float vx = veh[3*b], vy = veh[3*b+1], vz = veh[3*b+2];
    const int nU4 = npad >> 1;

    if (tid == 0) { s_minPacked = ~0ull; s_wcount = 0; }
    if (tid < NPART) hist32[tid] = 0;

    // block-wide: find bucket where cumulative hist count crosses remq
    auto find_bucket = [&](unsigned remq) {
        const int PER = NHIST / BLOCK;  // 4
        int base = tid * PER;
        unsigned c[PER];
        unsigned p = 0;
        #pragma unroll
        for (int i = 0; i < PER; i++) { c[i] = hist[base + i]; p += c[i]; }
        unsigned incl = p;
        #pragma unroll
        for (int d = 1; d < 64; d <<= 1) {
            unsigned n = __shfl_up(incl, d, 64);
            if (lane >= d) incl += n;
        }
        if (lane == 63) waveTot[wid] = incl;
        __syncthreads();
        if (tid == 0) {
            unsigned acc = 0;
            for (int w = 0; w < BLOCK / 64; w++) { waveBase[w] = acc; acc += waveTot[w]; }
        }
        __syncthreads();
        unsigned excl = waveBase[wid] + incl - p;
        if (excl < remq && remq <= excl + p) {
            unsigned cum = excl;
            #pragma unroll
            for (int i = 0; i < PER; i++) {
                if (cum + c[i] >= remq) { s_bucket = base + i; s_rem = remq - cum; s_bcount = c[i]; break; }
                cum += c[i];
            }
        }
        __syncthreads();
    };

    // ---- exact sample keys + rank (computed once) ----
    const unsigned myKey = key_of(fus, (int)(((long long)tid * nfus) / BLOCK), vx, vy, vz);
    skeys[tid] = myKey;
    __syncthreads();
    int myRank = 0;
    for (int k = 0; k < BLOCK; ++k) myRank += (skeys[k] < myKey) ? 1 : 0;
    __syncthreads();   // skeys reads done (hist reusable later)

    // ================== pivot + compressed scan + exact rescore, monotone retry ==================
    int sstar = SSTAR;
    int cnt = 0;
    bool needRadix = false;
    for (int attempt = 0; attempt < MAX_RETRY; ++attempt) {
        if (tid == 0) { s_pivot = 0; s_apx = 0; s_candCount = 0; }
        __syncthreads();
        if (myRank < sstar) atomicMax(&s_pivot, myKey);
        __syncthreads();
        const unsigned pivot = s_pivot;
        const float pf = __uint_as_float(pivot);
        const float thresh = pf + 0.75f * sqrtf(pf) + 0.25f;   // covers fp16 coord error

        // ---- single scan of compressed points (2 per uint4, lane-contiguous) ----
        for (int m = tid; m < nU4; m += BLOCK) {
            uint4 u = h4[m];
            float2 xy0 = h2f2(u.x); float z0 = h2f2(u.y).x;
            float2 xy1 = h2f2(u.z); float z1 = h2f2(u.w).x;
            float dx0 = xy0.x - vx, dy0 = xy0.y - vy, dz0 = z0 - vz;
            float dx1 = xy1.x - vx, dy1 = xy1.y - vy, dz1 = z1 - vz;
            float a0 = dx0*dx0 + dy0*dy0 + dz0*dz0;
            float a1 = dx1*dx1 + dy1*dy1 + dz1*dz1;
            if (a0 <= thresh) { int pos = atomicAdd(&s_apx, 1); if (pos < ACAP) acand[pos] = 2*m; }
            if (a1 <= thresh) { int pos = atomicAdd(&s_apx, 1); if (pos < ACAP) acand[pos] = 2*m + 1; }
        }
        __syncthreads();
        const int apx = s_apx;

        bool tooBig = (apx > ACAP);
        if (!tooBig) {
            // ---- exact rescore of candidates from original f32 array ----
            for (int i = tid; i < apx; i += BLOCK) {
                int j = acand[i];
                unsigned k = key_of(fus, j, vx, vy, vz);
                if (k <= pivot) {
                    int pos = atomicAdd(&s_candCount, 1);
                    if (pos < CAND_CAP) cand[pos] = ((ull)k << 32) | (unsigned)j;
                }
            }
            __syncthreads();
            cnt = s_candCount;
            if (cnt >= KTOP && cnt <= CAND_CAP) break;       // success
            tooBig = (cnt > CAND_CAP);
        }
        if (tooBig) { if (sstar <= 2)  { needRadix = true; break; } sstar >>= 1; }
        else        { if (sstar >= 256){ needRadix = true; break; } sstar <<= 1; }
        if (attempt == MAX_RETRY - 1) needRadix = true;
        __syncthreads();
    }

    unsigned rem = 0;

    if (!needRadix) {
        // ---- exact top-KTOP among cnt exact candidates (R6-proven path) ----
        ull lm = ~0ull;
        for (int i = tid; i < cnt; i += BLOCK) lm = min(lm, cand[i]);
        #pragma unroll
        for (int d = 32; d > 0; d >>= 1) {
            ull o = __shfl_xor(lm, d, 64);
            lm = (o < lm) ? o : lm;
        }
        if (lane == 0) atomicMin(&s_minPacked, lm);
        if (tid == 0) s_tc = 0;

        for (int i = tid; i < NHIST; i += BLOCK) hist[i] = 0;
        __syncthreads();
        for (int i = tid; i < cnt; i += BLOCK) atomicAdd(&hist[(unsigned)(cand[i] >> 53)], 1u);
        __syncthreads();
        find_bucket(KTOP);
        const unsigned T2 = s_bucket;
        rem = s_rem;
        const unsigned bcount = s_bcount;

        if (bcount <= TLIST_CAP) {
            for (int i = tid; i < cnt; i += BLOCK) {
                ull me = cand[i];
                unsigned bk = (unsigned)(me >> 53);
                if (bk < T2) {
                    int pos = atomicAdd(&s_wcount, 1);
                    if (pos < WCAP) wlist[pos] = (int)(me & 0xFFFFFFFFull);
                } else if (bk == T2) {
                    int pos = atomicAdd(&s_tc, 1);
                    if (pos < TLIST_CAP) tlist[pos] = me;
                }
            }
            __syncthreads();
            const int tc = s_tc;
            for (int i = tid; i < tc; i += BLOCK) {
                ull me = tlist[i];
                int rank = 0;
                for (int k2 = 0; k2 < tc; k2++) rank += (tlist[k2] < me) ? 1 : 0;
                if (rank < (int)rem) {
                    int pos = atomicAdd(&s_wcount, 1);
                    if (pos < WCAP) wlist[pos] = (int)(me & 0xFFFFFFFFull);
                }
            }
        } else {
            // rare: huge boundary bucket — rank against full cand
            for (int i = tid; i < cnt; i += BLOCK) {
                ull me = cand[i];
                if ((unsigned)(me >> 53) < T2) {
                    int pos = atomicAdd(&s_wcount, 1);
                    if (pos < WCAP) wlist[pos] = (int)(me & 0xFFFFFFFFull);
                }
            }
            __syncthreads();
            for (int i = tid; i < cnt; i += BLOCK) {
                ull me = cand[i];
                if ((unsigned)(me >> 53) == T2) {
                    int rank = 0;
                    for (int k2 = 0; k2 < cnt; k2++) {
                        ull o = cand[k2];
                        rank += ((unsigned)(o >> 53) == T2 && o < me) ? 1 : 0;
                    }
                    if (rank < (int)rem) {
                        int pos = atomicAdd(&s_wcount, 1);
                        if (pos < WCAP) wlist[pos] = (int)(me & 0xFFFFFFFFull);
                    }
                }
            }
        }
        __syncthreads();
    } else {
        // ---- exact radix-select fallback (never expected; exact f32 reloads) ----
        if (tid == 0) { s_candCount = 0; s_wcount = 0; }
        for (int i = tid; i < NHIST; i += BLOCK) hist[i] = 0;
        __syncthreads();
        for (int j = tid; j < nfus; j += BLOCK)
            atomicAdd(&hist[key_of(fus, j, vx, vy, vz) >> 21], 1u);
        __syncthreads();
        find_bucket(KTOP);
        unsigned T = s_bucket;
        rem = s_rem;
        unsigned bcount = s_bcount;
        int shift = 21;

        while (bcount > CAND_CAP && shift > 0) {
            int newshift = (shift > 11) ? (shift - 11) : 0;
            unsigned digmask = (1u << (shift - newshift)) - 1;
            __syncthreads();
            for (int i = tid; i < NHIST; i += BLOCK) hist[i] = 0;
            __syncthreads();
            for (int j = tid; j < nfus; j += BLOCK) {
                unsigned k = key_of(fus, j, vx, vy, vz);
                if ((k >> shift) == T) atomicAdd(&hist[(k >> newshift) & digmask], 1u);
            }
            __syncthreads();
            find_bucket(rem);
            T = (T << (shift - newshift)) | s_bucket;
            rem = s_rem;
            bcount = s_bcount;
            shift = newshift;
        }

        for (int j = tid; j < nfus; j += BLOCK) {
            unsigned k = key_of(fus, j, vx, vy, vz);
            unsigned hi = k >> shift;
            if (hi < T) {
                int pos = atomicAdd(&s_wcount, 1);
                if (pos < WCAP) wlist[pos] = j;
                atomicMin(&s_minPacked, ((ull)k << 32) | (unsigned)j);
            } else if (hi == T) {
                int pos = atomicAdd(&s_candCount, 1);
                if (pos < CAND_CAP) cand[pos] = ((ull)k << 32) | (unsigned)j;
                atomicMin(&s_minPacked, ((ull)k << 32) | (unsigned)j);
            }
        }
        __syncthreads();
        const int fcnt = s_candCount;
        if (fcnt <= CAND_CAP) {
            for (int i = tid; i < fcnt; i += BLOCK) {
                ull me = cand[i];
                int rank = 0;
                for (int k2 = 0; k2 < fcnt; k2++) rank += (cand[k2] < me) ? 1 : 0;
                if (rank < (int)rem) {
                    int pos = atomicAdd(&s_wcount, 1);
                    if (pos < WCAP) wlist[pos] = (int)(me & 0xFFFFFFFFull);
                }
            }
            __syncthreads();
        } else {
            // pathological: serial stable extraction among boundary keys
            const int idx0f = (int)(s_minPacked & 0xFFFFFFFFull);
            const float fq0x = fus[idx0f * 3], fq0y = fus[idx0f * 3 + 1], fq0z = fus[idx0f * 3 + 2];
            if (tid == 0) s_lowBound = 0;
            __syncthreads();
            for (unsigned itx = 0; itx < rem; ++itx) {
                if (tid == 0) s_serMin = ~0ull;
                __syncthreads();
                ull lowB = s_lowBound;
                ull lmx = ~0ull;
                for (int j = tid; j < nfus; j += BLOCK) {
                    unsigned k = key_of(fus, j, vx, vy, vz);
                    if ((k >> shift) == T) {
                        ull p = ((ull)k << 32) | (unsigned)j;
                        if (p >= lowB && p < lmx) lmx = p;
                    }
                }
                #pragma unroll
                for (int d = 32; d > 0; d >>= 1) {
                    ull o = __shfl_xor(lmx, d, 64);
                    lmx = (o < lmx) ? o : lmx;
                }
                if (lane == 0) atomicMin(&s_serMin, lmx);
                __syncthreads();
                if (tid == 0) {
                    int jm = (int)(s_serMin & 0xFFFFFFFFull);
                    float fx = fus[jm * 3], fy = fus[jm * 3 + 1], fz = fus[jm * 3 + 2];
                    int bin = compute_bin(__fsub_rn(fx, fq0x), __fsub_rn(fy, fq0y), __fsub_rn(fz, fq0z));
                    if (bin >= 0 && bin < NPART) hist32[bin] += 1u;
                    s_lowBound = s_serMin + 1;
                }
                __syncthreads();
            }
        }
    }

    // ---- common: q0 = stable nearest; winners -> shape-context bins ----
    const int idx0 = (int)(s_minPacked & 0xFFFFFFFFull);
    const float q0x = fus[idx0 * 3], q0y = fus[idx0 * 3 + 1], q0z = fus[idx0 * 3 + 2];
    {
        int wc = s_wcount; if (wc > WCAP) wc = WCAP;
        for (int i = tid; i < wc; i += BLOCK) {
            int j = wlist[i];
            float fx = fus[3 * j], fy = fus[3 * j + 1], fz = fus[3 * j + 2];
            int bin = compute_bin(__fsub_rn(fx, q0x), __fsub_rn(fy, q0y), __fsub_rn(fz, q0z));
            if (bin >= 0 && bin < NPART) atomicAdd(&hist32[bin], 1u);
        }
    }
    __syncthreads();

    // ---- epilogue (lanes 0..31 of wave 0): counts+1 -> L2-normalize*4 -> softmax ----
    if (tid < NPART) {
        float c = (float)hist32[tid] + 1.0f;
        float ss = __fmul_rn(c, c);
        #pragma unroll
        for (int d = 16; d > 0; d >>= 1) ss += __shfl_xor(ss, d, 64);
        float v = __fmul_rn(__fdiv_rn(c, sqrtf(ss)), 4.0f);
        float mx = v;
        #pragma unroll
        for (int d = 16; d > 0; d >>= 1) mx = fmaxf(mx, __shfl_xor(mx, d, 64));
        float e = expf(v - mx);
        float sum = e;
        #pragma unroll
        for (int d = 16; d > 0; d >>= 1) sum += __shfl_xor(sum, d, 64);
        out[b * NPART + tid] = __fdiv_rn(e, sum);
    }
}

extern "C" void kernel_launch(void* const* d_in, const int* in_sizes, int n_in,
                              void* d_out, int out_size, void* d_ws, size_t ws_size,
                              hipStream_t stream) {
    const float* veh = (const float*)d_in[0];   // (1024, 3)
    const float* fus = (const float*)d_in[1];   // (20000, 3)
    float* out = (float*)d_out;                 // (1024, 32)
    int nveh = in_sizes[0] / 3;
    int nfus = in_sizes[1] / 3;
    int npad = (nfus + 1) & ~1;                 // even # of 8B points (uint4 = 2 points)

    uint2* hbuf = (uint2*)d_ws;                 // 8 B * npad ( << ws_size )
    compress_kernel<<<(npad + 255) / 256, 256, 0, stream>>>(fus, hbuf, nfus, npad);
    shape_context_kernel<<<nveh, BLOCK, 0, stream>>>(veh, fus, (const uint4*)hbuf,
                                                     out, nfus, npad);
}